// Round 2
// baseline (35764.291 us; speedup 1.0000x reference)
//
#include <hip/hip_runtime.h>

// GLIF recurrent network: T=8192 sequential steps, N=1024 neurons.
// 128 single-wave blocks; wave owns 8 columns. lane = 8*rc + cl:
//   rc = lane>>3 : row chunk (rows rc*128 .. rc*128+128)
//   cl = lane&7  : local column; global col = blockIdx*8 + cl
// Cross-block exchange: tagged u64 (tag<<32 | f32bits), double-buffered by
// step parity, relaxed agent-scope atomics. No s_barrier / vmcnt drain in
// the step loop — the only fence is lgkmcnt(0) between LDS write and read.

#define T_STEPS 8192
#define N_NEUR  1024
#define NBLK    128
#define TPB     64

__global__ void glif_init(unsigned long long* __restrict__ buf) {
    int i = blockIdx.x * blockDim.x + threadIdx.x;
    if (i < N_NEUR) {
        buf[i] = 0ULL;                                // S_0: value 0.0f, tag 0
    } else if (i < 2 * N_NEUR) {
        buf[i] = 0xFFFFFFFF00000000ULL;               // odd buffer: invalid tag
    }
}

__launch_bounds__(TPB, 1)
__global__ void glif_main(const float* __restrict__ x_in,
                          const float* __restrict__ w,
                          const float* __restrict__ E_L_p,
                          const float* __restrict__ tau_m_p,
                          const float* __restrict__ G_p,
                          const float* __restrict__ R_I_p,
                          const float* __restrict__ f_v_p,
                          const float* __restrict__ f_I_p,
                          const float* __restrict__ dths_p,
                          const float* __restrict__ b_s_p,
                          const float* __restrict__ a_v_p,
                          const float* __restrict__ b_v_p,
                          const float* __restrict__ th_inf_p,
                          const float* __restrict__ dV_p,
                          const float* __restrict__ I_A_p,
                          float* __restrict__ out,
                          unsigned long long* __restrict__ buf) {
    const int lane = threadIdx.x;        // 0..63 (single wave)
    const int rc   = lane >> 3;          // row chunk 0..7
    const int cl   = lane & 7;           // local column 0..7
    const int col  = blockIdx.x * 8 + cl;

    // Swizzled LDS: logical float4-chunk c lives at slot c ^ ((c>>5)&7).
    // Reader (iteration m, chunk rc*32+m): 8 distinct rc -> 8 distinct bank
    // groups, each broadcast to 8 lanes -> conflict-free ds_read_b128.
    __shared__ float4 ix[256];

    // ---- one-time: this lane's 128 w values (rows rc*128..+128, column col)
    float wreg[128];
#pragma unroll
    for (int j = 0; j < 128; ++j) {
        int r = rc * 128 + j;
        float wv = w[(size_t)r * N_NEUR + col];
        wreg[j] = (r == col) ? 0.0f : wv;   // zero diagonal (self-recurrence mask)
    }

    // ---- per-column params, loaded redundantly by all 8 lanes of the group
    const float E_L    = E_L_p[col];
    const float inv_tau = 1.0f / tau_m_p[col];
    const float Gc     = G_p[col];
    const float R_I    = R_I_p[col];
    const float f_v    = f_v_p[col];
    const float om_fI  = 1.0f - f_I_p[col];
    const float dths   = dths_p[col];
    const float om_bs  = 1.0f - b_s_p[col];
    const float a_v    = a_v_p[col];
    const float b_v    = b_v_p[col];
    const float th_inf = th_inf_p[col];
    const float dV     = dV_p[col];
    const float I_A    = I_A_p[col];

    float v = E_L, th_s = 30.0f, th_v = 1.0f, I_own = 0.0f;
    float xnext = x_in[col];             // prefetch x for t=0

    float* __restrict__ vs_out = out;
    float* __restrict__ sp_out = out + (size_t)T_STEPS * N_NEUR;

    for (int t = 0; t < T_STEPS; ++t) {
        // ---- phase A: poll 16 tagged values (rows lane*16..+16)
        unsigned long long* src = buf + (size_t)(t & 1) * N_NEUR + lane * 16;
        float vals[16];
        unsigned got = 0;
        while (got != 0xFFFFu) {
#pragma unroll
            for (int k = 0; k < 16; ++k) {
                if (!(got & (1u << k))) {
                    unsigned long long u = __hip_atomic_load(
                        src + k, __ATOMIC_RELAXED, __HIP_MEMORY_SCOPE_AGENT);
                    if ((unsigned)(u >> 32) == (unsigned)t) {
                        vals[k] = __uint_as_float((unsigned)(u & 0xFFFFFFFFu));
                        got |= (1u << k);
                    }
                }
            }
        }

        // ---- stage to LDS (swizzled), then x-prefetch (fire-and-forget)
#pragma unroll
        for (int i = 0; i < 4; ++i) {
            int c = 4 * lane + i;
            int p = c ^ ((c >> 5) & 7);
            ix[p] = make_float4(vals[4*i], vals[4*i+1], vals[4*i+2], vals[4*i+3]);
        }
        float xt = xnext;
        {
            int tn = (t + 1 < T_STEPS) ? (t + 1) : t;
            xnext = x_in[(size_t)tn * N_NEUR + col];   // latency hidden by matvec
        }
        // single-wave fence: LDS writes (all lanes) complete before reads.
        // DS ops are in-order per wave; lgkmcnt(0) drains the writes. No
        // s_barrier, no vmcnt drain (keeps stores/prefetch off critical path).
        asm volatile("s_waitcnt lgkmcnt(0)" ::: "memory");
        __builtin_amdgcn_sched_barrier(0);

        // ---- phase B: 128 MACs, 4 independent accumulator chains
        float a0 = 0.f, a1 = 0.f, a2 = 0.f, a3 = 0.f;
#pragma unroll
        for (int m = 0; m < 32; ++m) {
            float4 q = ix[rc * 32 + (m ^ rc)];   // swizzled read, conflict-free
            a0 = fmaf(wreg[4*m+0], q.x, a0);
            a1 = fmaf(wreg[4*m+1], q.y, a1);
            a2 = fmaf(wreg[4*m+2], q.z, a2);
            a3 = fmaf(wreg[4*m+3], q.w, a3);
        }
        float acc = (a0 + a1) + (a2 + a3);
        // fold across the 8 row-chunks (lanes differing in bits 3..5)
        acc += __shfl_xor(acc, 8, 64);
        acc += __shfl_xor(acc, 16, 64);
        acc += __shfl_xor(acc, 32, 64);
        // all 8 lanes of a column group now hold bit-identical sums

        // ---- phase C: GLIF elementwise, computed redundantly on all lanes
        float I = acc + 0.85f * xt;
        float v_next = v + (I * R_I - Gc * (v - E_L)) * inv_tau;
        float thr = th_s + th_v;
        float z = v_next - thr;
        float soft = 1.0f / (1.0f + __expf(-z));   // surrogate spike
        bool  sp = (v_next >= thr);                 // hard spike
        float v_reset = E_L + f_v * (v - E_L) - dV;
        float v_new = sp ? v_reset : v_next;
        th_s = om_bs * th_s + (sp ? dths : 0.0f);
        float d_thv = a_v * (v_new - E_L) - b_v * (th_v - th_inf);
        th_v = th_v + (sp ? 0.0f : d_thv);
        I_own = om_fI * I_own + soft * I_A;
        v = v_new;

        if (rc == 0) {   // one lane per column: output + publish (fire-and-forget)
            __builtin_nontemporal_store(v_new, &vs_out[(size_t)t * N_NEUR + col]);
            __builtin_nontemporal_store(soft, &sp_out[(size_t)t * N_NEUR + col]);
            unsigned long long pk =
                ((unsigned long long)(unsigned)(t + 1) << 32) |
                (unsigned long long)__float_as_uint(I_own);
            __hip_atomic_store(buf + (size_t)((t + 1) & 1) * N_NEUR + col, pk,
                               __ATOMIC_RELAXED, __HIP_MEMORY_SCOPE_AGENT);
        }
    }
}

extern "C" void kernel_launch(void* const* d_in, const int* in_sizes, int n_in,
                              void* d_out, int out_size, void* d_ws, size_t ws_size,
                              hipStream_t stream) {
    const float* x_in   = (const float*)d_in[0];
    const float* w      = (const float*)d_in[1];
    const float* E_L    = (const float*)d_in[2];
    const float* tau_m  = (const float*)d_in[3];
    const float* G      = (const float*)d_in[4];
    const float* R_I    = (const float*)d_in[5];
    const float* f_v    = (const float*)d_in[6];
    const float* f_I    = (const float*)d_in[7];
    const float* dths   = (const float*)d_in[8];
    const float* b_s    = (const float*)d_in[9];
    const float* a_v    = (const float*)d_in[10];
    const float* b_v    = (const float*)d_in[11];
    const float* th_inf = (const float*)d_in[12];
    const float* dV     = (const float*)d_in[13];
    const float* I_A    = (const float*)d_in[14];

    float* out = (float*)d_out;
    unsigned long long* buf = (unsigned long long*)d_ws;  // 2 * 1024 u64 = 16 KB

    glif_init<<<8, 256, 0, stream>>>(buf);
    glif_main<<<NBLK, TPB, 0, stream>>>(x_in, w, E_L, tau_m, G, R_I, f_v, f_I,
                                        dths, b_s, a_v, b_v, th_inf, dV, I_A,
                                        out, buf);
}

// Round 3
// 23109.369 us; speedup vs baseline: 1.5476x; 1.5476x over previous
//
#include <hip/hip_runtime.h>

// GLIF recurrent network: T=8192 sequential steps, N=1024 neurons.
// 32 blocks x 512 threads (8 waves). Wave w owns row slice [128w,128w+128):
//   - polls 2 tagged u64/thread (wave-private 1KB slice, double-pumped)
//   - stages to its own LDS slice (single-wave lgkmcnt fence, no barrier)
//   - 64 MACs/lane (4 chains) for all 32 block columns, fold shfl_xor(32)
// One raw s_barrier per step (lgkmcnt-only wait, NO vmcnt drain). Lanes 0..3
// of wave w own columns 4w..4w+4: sum 8 partials, elementwise, publish.
// Cross-block exchange: tagged u64 (tag<<32 | f32bits), double-buffered by
// step parity, relaxed agent-scope atomics.

#define T_STEPS 8192
#define N_NEUR  1024
#define NBLK    32
#define TPB     512

typedef unsigned long long ull;

__global__ void glif_init(ull* __restrict__ buf) {
    int i = blockIdx.x * blockDim.x + threadIdx.x;
    if (i < N_NEUR) {
        buf[i] = 0ULL;                                // S_0: value 0.0f, tag 0
    } else if (i < 2 * N_NEUR) {
        buf[i] = 0xFFFFFFFF00000000ULL;               // odd buffer: invalid tag
    }
}

__launch_bounds__(TPB, 2)
__global__ void glif_main(const float* __restrict__ x_in,
                          const float* __restrict__ w_p,
                          const float* __restrict__ E_L_p,
                          const float* __restrict__ tau_m_p,
                          const float* __restrict__ G_p,
                          const float* __restrict__ R_I_p,
                          const float* __restrict__ f_v_p,
                          const float* __restrict__ f_I_p,
                          const float* __restrict__ dths_p,
                          const float* __restrict__ b_s_p,
                          const float* __restrict__ a_v_p,
                          const float* __restrict__ b_v_p,
                          const float* __restrict__ th_inf_p,
                          const float* __restrict__ dV_p,
                          const float* __restrict__ I_A_p,
                          float* __restrict__ out,
                          ull* __restrict__ buf) {
    const int tid  = threadIdx.x;
    const int wv   = tid >> 6;           // wave 0..7, owns rows [128wv,128wv+128)
    const int lane = tid & 63;
    const int c    = lane & 31;          // FMA column (block-local)
    const int h    = lane >> 5;          // row half within wave slice
    const int colF = blockIdx.x * 32 + c;        // global FMA column
    const int rbase = wv * 128 + h * 64;         // this lane's 64 FMA rows

    __shared__ float ix[N_NEUR];         // staged I_add, wave w owns [128w,128w+128)
    __shared__ float red[8][32];         // per-wave partial sums per column

    // ---- one-time: 64 w values (rows rbase..rbase+64, column colF), coalesced
    float wreg[64];
#pragma unroll
    for (int j = 0; j < 64; ++j) {
        int r = rbase + j;
        float wval = w_p[(size_t)r * N_NEUR + colF];
        wreg[j] = (r == colF) ? 0.0f : wval;   // zero diagonal (self-recurrence)
    }

    // ---- lanes 0..3 of wave wv own columns 4wv+0..3 (state + publish)
    const bool pub  = (lane < 4);
    const int  cp   = wv * 4 + lane;             // block-local publish column
    const int  colP = blockIdx.x * 32 + cp;      // global publish column

    float E_L = 0.f, inv_tau = 0.f, Gc = 0.f, R_I = 0.f, f_v = 0.f, om_fI = 0.f;
    float dths = 0.f, om_bs = 0.f, a_v = 0.f, b_v = 0.f, th_inf = 0.f, dV = 0.f, I_A = 0.f;
    float v = 0.f, th_s = 0.f, th_v = 0.f, I_own = 0.f, xnext = 0.f;
    if (pub) {
        E_L     = E_L_p[colP];
        inv_tau = 1.0f / tau_m_p[colP];
        Gc      = G_p[colP];
        R_I     = R_I_p[colP];
        f_v     = f_v_p[colP];
        om_fI   = 1.0f - f_I_p[colP];
        dths    = dths_p[colP];
        om_bs   = 1.0f - b_s_p[colP];
        a_v     = a_v_p[colP];
        b_v     = b_v_p[colP];
        th_inf  = th_inf_p[colP];
        dV      = dV_p[colP];
        I_A     = I_A_p[colP];
        v = E_L; th_s = 30.0f; th_v = 1.0f; I_own = 0.0f;
        xnext = x_in[colP];                      // prefetch x for t=0
    }

    float* __restrict__ vs_out = out;
    float* __restrict__ sp_out = out + (size_t)T_STEPS * N_NEUR;

    for (int t = 0; t < T_STEPS; ++t) {
        // ---- phase A: poll 2 tagged u64 (rows 128wv + 2*lane), double-pumped
        ull* src = buf + (size_t)(t & 1) * N_NEUR + wv * 128 + lane * 2;
        float f0, f1;
        {
            ull a0 = __hip_atomic_load(src + 0, __ATOMIC_RELAXED, __HIP_MEMORY_SCOPE_AGENT);
            ull a1 = __hip_atomic_load(src + 1, __ATOMIC_RELAXED, __HIP_MEMORY_SCOPE_AGENT);
            bool g0 = false, g1 = false;
            for (;;) {
                // next round in flight while checking current (halves detect jitter)
                ull b0 = __hip_atomic_load(src + 0, __ATOMIC_RELAXED, __HIP_MEMORY_SCOPE_AGENT);
                ull b1 = __hip_atomic_load(src + 1, __ATOMIC_RELAXED, __HIP_MEMORY_SCOPE_AGENT);
                if (!g0 && (unsigned)(a0 >> 32) == (unsigned)t) { f0 = __uint_as_float((unsigned)a0); g0 = true; }
                if (!g1 && (unsigned)(a1 >> 32) == (unsigned)t) { f1 = __uint_as_float((unsigned)a1); g1 = true; }
                if (g0 && g1) break;
                a0 = b0; a1 = b1;
            }
        }

        // ---- stage to this wave's LDS slice (no cross-wave barrier needed)
        ((float2*)ix)[wv * 64 + lane] = make_float2(f0, f1);
        asm volatile("s_waitcnt lgkmcnt(0)" ::: "memory");   // wave's ds_writes done
        __builtin_amdgcn_sched_barrier(0);

        // ---- phase B: 64 MACs, 4 independent chains, from own slice (broadcast reads)
        float s0 = 0.f, s1 = 0.f, s2 = 0.f, s3 = 0.f;
        const float4* q4 = (const float4*)(ix + rbase);
#pragma unroll
        for (int m = 0; m < 16; ++m) {
            float4 q = q4[m];
            s0 = fmaf(wreg[4 * m + 0], q.x, s0);
            s1 = fmaf(wreg[4 * m + 1], q.y, s1);
            s2 = fmaf(wreg[4 * m + 2], q.z, s2);
            s3 = fmaf(wreg[4 * m + 3], q.w, s3);
        }
        float acc = (s0 + s1) + (s2 + s3);
        acc += __shfl_xor(acc, 32, 64);          // fold the two 64-row halves
        if (lane < 32) red[wv][c] = acc;         // wave's 128-row partial per column

        // ---- one barrier per step: lgkmcnt-only (stores/prefetch stay in flight)
        asm volatile("s_waitcnt lgkmcnt(0)" ::: "memory");
        __builtin_amdgcn_s_barrier();
        __builtin_amdgcn_sched_barrier(0);

        // ---- phase C: owner lanes finish their column
        if (pub) {
            float r01 = red[0][cp] + red[1][cp];
            float r23 = red[2][cp] + red[3][cp];
            float r45 = red[4][cp] + red[5][cp];
            float r67 = red[6][cp] + red[7][cp];
            float I = ((r01 + r23) + (r45 + r67)) + 0.85f * xnext;

            float v_next = v + (I * R_I - Gc * (v - E_L)) * inv_tau;
            float thr = th_s + th_v;
            float z = v_next - thr;
            float soft = 1.0f / (1.0f + __expf(-z));   // surrogate spike
            // publish as early as possible: I_own only needs soft
            I_own = om_fI * I_own + soft * I_A;
            ull pk = ((ull)(unsigned)(t + 1) << 32) | (ull)__float_as_uint(I_own);
            __hip_atomic_store(buf + (size_t)((t + 1) & 1) * N_NEUR + colP, pk,
                               __ATOMIC_RELAXED, __HIP_MEMORY_SCOPE_AGENT);

            bool  sp = (v_next >= thr);                 // hard spike
            float v_reset = E_L + f_v * (v - E_L) - dV;
            float v_new = sp ? v_reset : v_next;
            th_s = om_bs * th_s + (sp ? dths : 0.0f);
            float d_thv = a_v * (v_new - E_L) - b_v * (th_v - th_inf);
            th_v = th_v + (sp ? 0.0f : d_thv);
            v = v_new;

            __builtin_nontemporal_store(v_new, &vs_out[(size_t)t * N_NEUR + colP]);
            __builtin_nontemporal_store(soft, &sp_out[(size_t)t * N_NEUR + colP]);

            int tn = (t + 1 < T_STEPS) ? (t + 1) : t;
            xnext = x_in[(size_t)tn * N_NEUR + colP];   // fire-and-forget prefetch
        }
    }
}

extern "C" void kernel_launch(void* const* d_in, const int* in_sizes, int n_in,
                              void* d_out, int out_size, void* d_ws, size_t ws_size,
                              hipStream_t stream) {
    const float* x_in   = (const float*)d_in[0];
    const float* w      = (const float*)d_in[1];
    const float* E_L    = (const float*)d_in[2];
    const float* tau_m  = (const float*)d_in[3];
    const float* G      = (const float*)d_in[4];
    const float* R_I    = (const float*)d_in[5];
    const float* f_v    = (const float*)d_in[6];
    const float* f_I    = (const float*)d_in[7];
    const float* dths   = (const float*)d_in[8];
    const float* b_s    = (const float*)d_in[9];
    const float* a_v    = (const float*)d_in[10];
    const float* b_v    = (const float*)d_in[11];
    const float* th_inf = (const float*)d_in[12];
    const float* dV     = (const float*)d_in[13];
    const float* I_A    = (const float*)d_in[14];

    float* out = (float*)d_out;
    ull* buf = (ull*)d_ws;   // 2 * 1024 u64 = 16 KB

    glif_init<<<8, 256, 0, stream>>>(buf);
    glif_main<<<NBLK, TPB, 0, stream>>>(x_in, w, E_L, tau_m, G, R_I, f_v, f_I,
                                        dths, b_s, a_v, b_v, th_inf, dV, I_A,
                                        out, buf);
}

// Round 4
// 15831.725 us; speedup vs baseline: 2.2590x; 1.4597x over previous
//
#include <hip/hip_runtime.h>

// GLIF recurrent network: T=8192 sequential steps, N=1024 neurons.
// R1 skeleton (32 blocks x 256 threads, 4 waves, block owns 32 columns) with:
//   - inline-asm poll: 4 loads back-to-back + ONE vmcnt(0) per round
//   - per-consumer private buffers: producer fans out its 32 tagged values to
//     all 32 consumer copies (1 writer + 1 reader block per cache line)
//   - raw s_barrier with lgkmcnt-only waits (no vmcnt drain on critical path)
//   - publish-first phase C, fan-out spread across the 4 waves (8 dests each)
// Entry: u64 = (tag=step)<<32 | f32 bits, double-buffered by step parity.

#define T_STEPS 8192
#define N_NEUR  1024
#define NBLK    32
#define TPB     256
#define PSTRIDE (NBLK * N_NEUR)          // u64 entries per parity (32 copies)

typedef unsigned long long ull;

__global__ void glif_init(ull* __restrict__ buf) {
    int i = blockIdx.x * blockDim.x + threadIdx.x;
    if (i < PSTRIDE) {
        buf[i] = 0ULL;                                // S_0: value 0.0f, tag 0
    } else if (i < 2 * PSTRIDE) {
        buf[i] = 0xFFFFFFFF00000000ULL;               // odd parity: invalid tag
    }
}

__launch_bounds__(TPB, 1)
__global__ void glif_main(const float* __restrict__ x_in,
                          const float* __restrict__ w_p,
                          const float* __restrict__ E_L_p,
                          const float* __restrict__ tau_m_p,
                          const float* __restrict__ G_p,
                          const float* __restrict__ R_I_p,
                          const float* __restrict__ f_v_p,
                          const float* __restrict__ f_I_p,
                          const float* __restrict__ dths_p,
                          const float* __restrict__ b_s_p,
                          const float* __restrict__ a_v_p,
                          const float* __restrict__ b_v_p,
                          const float* __restrict__ th_inf_p,
                          const float* __restrict__ dV_p,
                          const float* __restrict__ I_A_p,
                          float* __restrict__ out,
                          ull* __restrict__ buf) {
    const int tid  = threadIdx.x;
    const int wv   = tid >> 6;                 // wave 0..3
    const int lane = tid & 63;
    const int colL = lane & 31;                // block-local column
    const int col  = blockIdx.x * 32 + colL;   // global column
    const int ibase = wv * 256 + (lane >> 5) * 128;  // this lane's 128 FMA rows

    __shared__ float ix[N_NEUR];               // staged I_add for this step
    __shared__ float red[4][32];               // per-wave partial sums

    // ---- one-time: 128 w values (rows ibase..+128, column col)
    float wreg[128];
#pragma unroll
    for (int j = 0; j < 128; ++j) {
        int r = ibase + j;
        float wval = w_p[(size_t)r * N_NEUR + col];
        wreg[j] = (r == col) ? 0.0f : wval;    // zero diagonal (self-recurrence)
    }

    // ---- lanes<32 of EVERY wave replicate the state for column `col`
    // (deterministic identical updates; wave w fans out to consumers 8w..8w+8,
    //  wave 0 additionally writes the vs/spikes outputs)
    const bool own = (lane < 32);
    float E_L = 0.f, inv_tau = 0.f, Gc = 0.f, R_I = 0.f, f_v = 0.f, om_fI = 0.f;
    float dths = 0.f, om_bs = 0.f, a_v = 0.f, b_v = 0.f, th_inf = 0.f, dV = 0.f, I_A = 0.f;
    float v = 0.f, th_s = 0.f, th_v = 0.f, I_own = 0.f, xnext = 0.f;
    if (own) {
        E_L     = E_L_p[col];
        inv_tau = 1.0f / tau_m_p[col];
        Gc      = G_p[col];
        R_I     = R_I_p[col];
        f_v     = f_v_p[col];
        om_fI   = 1.0f - f_I_p[col];
        dths    = dths_p[col];
        om_bs   = 1.0f - b_s_p[col];
        a_v     = a_v_p[col];
        b_v     = b_v_p[col];
        th_inf  = th_inf_p[col];
        dV      = dV_p[col];
        I_A     = I_A_p[col];
        v = E_L; th_s = 30.0f; th_v = 1.0f; I_own = 0.0f;
        xnext = x_in[col];                     // x for t=0
    }

    float* __restrict__ vs_out = out;
    float* __restrict__ sp_out = out + (size_t)T_STEPS * N_NEUR;

    for (int t = 0; t < T_STEPS; ++t) {
        // ---- phase A: poll this block's PRIVATE copy, 4 tagged u64 / thread.
        // 4 loads in flight, one vmcnt(0), check all 4 -> round ~= 1 L3 latency.
        const ull* src = buf + (size_t)(t & 1) * PSTRIDE
                             + (size_t)blockIdx.x * N_NEUR + tid * 4;
        ull u0, u1, u2, u3;
        const unsigned ut = (unsigned)t;
        for (;;) {
            asm volatile(
                "global_load_dwordx2 %0, %4, off sc0 sc1\n\t"
                "global_load_dwordx2 %1, %4, off offset:8 sc0 sc1\n\t"
                "global_load_dwordx2 %2, %4, off offset:16 sc0 sc1\n\t"
                "global_load_dwordx2 %3, %4, off offset:24 sc0 sc1\n\t"
                "s_waitcnt vmcnt(0)"
                : "=&v"(u0), "=&v"(u1), "=&v"(u2), "=&v"(u3)
                : "v"(src)
                : "memory");
            bool ok = ((unsigned)(u0 >> 32) == ut) & ((unsigned)(u1 >> 32) == ut) &
                      ((unsigned)(u2 >> 32) == ut) & ((unsigned)(u3 >> 32) == ut);
            if (ok) break;
        }
        ((float4*)ix)[tid] = make_float4(__uint_as_float((unsigned)u0),
                                         __uint_as_float((unsigned)u1),
                                         __uint_as_float((unsigned)u2),
                                         __uint_as_float((unsigned)u3));

        // sync1: LDS staged. lgkm-only wait; NO vmcnt drain.
        asm volatile("s_waitcnt lgkmcnt(0)" ::: "memory");
        __builtin_amdgcn_s_barrier();
        __builtin_amdgcn_sched_barrier(0);

        // x-prefetch for NEXT step (fire-and-forget; never drained by a barrier,
        // fully retired long before next step's poll succeeds)
        float xt = xnext;
        if (own) {
            int tn = (t + 1 < T_STEPS) ? (t + 1) : t;
            xnext = x_in[(size_t)tn * N_NEUR + col];
        }

        // ---- phase B: 128 MACs, 4 independent chains (broadcast LDS reads)
        float s0 = 0.f, s1 = 0.f, s2 = 0.f, s3 = 0.f;
        const float4* q4 = (const float4*)(ix + ibase);
#pragma unroll
        for (int m = 0; m < 32; ++m) {
            float4 q = q4[m];
            s0 = fmaf(wreg[4 * m + 0], q.x, s0);
            s1 = fmaf(wreg[4 * m + 1], q.y, s1);
            s2 = fmaf(wreg[4 * m + 2], q.z, s2);
            s3 = fmaf(wreg[4 * m + 3], q.w, s3);
        }
        float acc = (s0 + s1) + (s2 + s3);
        acc += __shfl_xor(acc, 32, 64);        // fold the two 128-row halves
        if (lane < 32) red[wv][colL] = acc;

        // sync2: red ready. lgkm-only wait.
        asm volatile("s_waitcnt lgkmcnt(0)" ::: "memory");
        __builtin_amdgcn_s_barrier();
        __builtin_amdgcn_sched_barrier(0);

        // ---- phase C: replicated elementwise; publish FIRST, then state/outputs
        if (own) {
            float I = (red[0][colL] + red[1][colL]) + (red[2][colL] + red[3][colL])
                      + 0.85f * xt;
            float v_next = v + (I * R_I - Gc * (v - E_L)) * inv_tau;
            float thr = th_s + th_v;
            float z = v_next - thr;
            float soft = 1.0f / (1.0f + __expf(-z));   // surrogate spike
            I_own = om_fI * I_own + soft * I_A;

            // fan-out publish: wave wv serves consumers 8*wv .. 8*wv+8
            ull pk = ((ull)(unsigned)(t + 1) << 32) | (ull)__float_as_uint(I_own);
            ull* dst = buf + (size_t)((t + 1) & 1) * PSTRIDE
                           + (size_t)(wv * 8) * N_NEUR + col;
#pragma unroll
            for (int k = 0; k < 8; ++k) {
                __hip_atomic_store(dst + (size_t)k * N_NEUR, pk,
                                   __ATOMIC_RELAXED, __HIP_MEMORY_SCOPE_AGENT);
            }

            // state update + outputs (off the publish critical path)
            bool  sp = (v_next >= thr);                 // hard spike
            float v_reset = E_L + f_v * (v - E_L) - dV;
            float v_new = sp ? v_reset : v_next;
            th_s = om_bs * th_s + (sp ? dths : 0.0f);
            float d_thv = a_v * (v_new - E_L) - b_v * (th_v - th_inf);
            th_v = th_v + (sp ? 0.0f : d_thv);
            v = v_new;

            if (wv == 0) {
                __builtin_nontemporal_store(v_new, &vs_out[(size_t)t * N_NEUR + col]);
                __builtin_nontemporal_store(soft, &sp_out[(size_t)t * N_NEUR + col]);
            }
        }
    }
}

extern "C" void kernel_launch(void* const* d_in, const int* in_sizes, int n_in,
                              void* d_out, int out_size, void* d_ws, size_t ws_size,
                              hipStream_t stream) {
    const float* x_in   = (const float*)d_in[0];
    const float* w      = (const float*)d_in[1];
    const float* E_L    = (const float*)d_in[2];
    const float* tau_m  = (const float*)d_in[3];
    const float* G      = (const float*)d_in[4];
    const float* R_I    = (const float*)d_in[5];
    const float* f_v    = (const float*)d_in[6];
    const float* f_I    = (const float*)d_in[7];
    const float* dths   = (const float*)d_in[8];
    const float* b_s    = (const float*)d_in[9];
    const float* a_v    = (const float*)d_in[10];
    const float* b_v    = (const float*)d_in[11];
    const float* th_inf = (const float*)d_in[12];
    const float* dV     = (const float*)d_in[13];
    const float* I_A    = (const float*)d_in[14];

    float* out = (float*)d_out;
    ull* buf = (ull*)d_ws;   // 2 parities * 32 copies * 1024 * 8B = 512 KB

    glif_init<<<(2 * PSTRIDE + TPB - 1) / TPB, TPB, 0, stream>>>(buf);
    glif_main<<<NBLK, TPB, 0, stream>>>(x_in, w, E_L, tau_m, G, R_I, f_v, f_I,
                                        dths, b_s, a_v, b_v, th_inf, dV, I_A,
                                        out, buf);
}